// Round 1
// baseline (762.600 us; speedup 1.0000x reference)
//
#include <hip/hip_runtime.h>

typedef __attribute__((ext_vector_type(8))) __bf16 bf16x8;
typedef __attribute__((ext_vector_type(4))) __bf16 bf16x4;
typedef __attribute__((ext_vector_type(4))) float f32x4;

static constexpr int kB = 4, kT = 2048, kD = 1024, kH = 16, kDH = 64;
static constexpr int kC = 32000, kM = 8192, k3D = 3072;

#define MFMA16(a, b, c) __builtin_amdgcn_mfma_f32_16x16x32_bf16((a), (b), (c), 0, 0, 0)

// ---------------- embed: h[b,t,:] = embed_W[tok[b,t],:] + pos_W[t,:] ----------------
__global__ __launch_bounds__(256) void embed_kernel(const int* __restrict__ tok,
                                                    const float* __restrict__ embW,
                                                    const float* __restrict__ posW,
                                                    float* __restrict__ h) {
  const int row = blockIdx.x;           // b*T + t
  const int t = row & (kT - 1);
  const int tk = tok[row];
  const f32x4 e = ((const f32x4*)(embW + (size_t)tk * kD))[threadIdx.x];
  const f32x4 p = ((const f32x4*)(posW + (size_t)t * kD))[threadIdx.x];
  ((f32x4*)(h + (size_t)row * kD))[threadIdx.x] = e + p;
}

// ---------------- LayerNorm over D=1024; one block (256 thr) per row ----------------
template <bool BF16OUT>
__global__ __launch_bounds__(256) void ln_kernel(const float* __restrict__ x,
                                                 const float* __restrict__ g,
                                                 const float* __restrict__ bb,
                                                 void* __restrict__ outp) {
  const int row = blockIdx.x, tid = threadIdx.x;
  const f32x4 xv = ((const f32x4*)(x + (size_t)row * kD))[tid];
  float s  = xv[0] + xv[1] + xv[2] + xv[3];
  float s2 = xv[0]*xv[0] + xv[1]*xv[1] + xv[2]*xv[2] + xv[3]*xv[3];
  #pragma unroll
  for (int off = 1; off < 64; off <<= 1) {
    s  += __shfl_xor(s, off);
    s2 += __shfl_xor(s2, off);
  }
  __shared__ float red[8];
  const int w = tid >> 6;
  if ((tid & 63) == 0) { red[w*2] = s; red[w*2+1] = s2; }
  __syncthreads();
  s  = red[0] + red[2] + red[4] + red[6];
  s2 = red[1] + red[3] + red[5] + red[7];
  const float mu  = s * (1.f / kD);
  const float var = s2 * (1.f / kD) - mu * mu;
  const float rs  = rsqrtf(var + 1e-5f);
  const f32x4 gv = ((const f32x4*)g)[tid];
  const f32x4 bv = ((const f32x4*)bb)[tid];
  if constexpr (BF16OUT) {
    bf16x4 o;
    #pragma unroll
    for (int i = 0; i < 4; i++) o[i] = (__bf16)((xv[i] - mu) * rs * gv[i] + bv[i]);
    ((bf16x4*)((__bf16*)outp + (size_t)row * kD))[tid] = o;
  } else {
    f32x4 o;
    #pragma unroll
    for (int i = 0; i < 4; i++) o[i] = (xv[i] - mu) * rs * gv[i] + bv[i];
    ((f32x4*)((float*)outp + (size_t)row * kD))[tid] = o;
  }
}

// ---------------- W [K][N] f32  ->  WT [N][K] bf16 (32x32 LDS tiles) ----------------
__global__ __launch_bounds__(256) void transpose_w_kernel(const float* __restrict__ W,
                                                          __bf16* __restrict__ WT,
                                                          int K, int N) {
  __shared__ float sh[32][33];
  const int tx = threadIdx.x & 31, ty = threadIdx.x >> 5;  // 32 x 8
  const int ntile = N >> 5;
  const int c0 = (blockIdx.x % ntile) << 5;
  const int r0 = (blockIdx.x / ntile) << 5;
  #pragma unroll
  for (int i = 0; i < 4; i++) {
    const int r = ty + i * 8;
    sh[r][tx] = W[(size_t)(r0 + r) * N + c0 + tx];
  }
  __syncthreads();
  #pragma unroll
  for (int i = 0; i < 4; i++) {
    const int cc = ty + i * 8;
    WT[(size_t)(c0 + cc) * K + r0 + tx] = (__bf16)sh[tx][cc];
  }
}

// ---------------- GEMM: C[M,N] = A[M,K](bf16) @ BT[N,K]^T(bf16) + bias ----------------
// OUT_BF16: outb = bf16(acc+bias).  else: outf = acc + bias + resid (f32).
// 256 thr = 4 waves (2x2), tile 128x128, BK=64, LDS row pad -> 72 (16B aligned, <=2-way bank).
__global__ __launch_bounds__(256) void gemm_dummy() {}  // (anchor; real kernel below)

template <bool OUT_BF16>
__global__ __launch_bounds__(256) void gemm_bt_kernel(const __bf16* __restrict__ A,
                                                      const __bf16* __restrict__ BT,
                                                      const float* __restrict__ bias,
                                                      const float* resid,
                                                      float* outf,
                                                      __bf16* outb,
                                                      int M, int N, int K) {
  constexpr int LDK = 72;
  __shared__ __bf16 As[128 * LDK];
  __shared__ __bf16 Bs[128 * LDK];
  const int tid = threadIdx.x;
  const int lane = tid & 63, w = tid >> 6;
  const int nbn = N >> 7;
  const int bm = blockIdx.x / nbn, bn = blockIdx.x % nbn;
  const int wr = (w >> 1) * 64, wc = (w & 1) * 64;
  const int lrow = lane & 15, lk = (lane >> 4) * 8;

  f32x4 acc[4][4] = {};

  for (int k0 = 0; k0 < K; k0 += 64) {
    bf16x8 ar[4], br[4];
    #pragma unroll
    for (int q = 0; q < 4; q++) {
      const int c = tid + 256 * q;
      const int row = c >> 3, col = (c & 7) * 8;
      ar[q] = *(const bf16x8*)(A  + (size_t)(bm * 128 + row) * K + k0 + col);
      br[q] = *(const bf16x8*)(BT + (size_t)(bn * 128 + row) * K + k0 + col);
    }
    __syncthreads();
    #pragma unroll
    for (int q = 0; q < 4; q++) {
      const int c = tid + 256 * q;
      const int row = c >> 3, col = (c & 7) * 8;
      *(bf16x8*)(As + row * LDK + col) = ar[q];
      *(bf16x8*)(Bs + row * LDK + col) = br[q];
    }
    __syncthreads();
    #pragma unroll
    for (int ks = 0; ks < 2; ks++) {
      bf16x8 af[4], bf[4];
      #pragma unroll
      for (int mt = 0; mt < 4; mt++)
        af[mt] = *(const bf16x8*)(As + (wr + mt * 16 + lrow) * LDK + ks * 32 + lk);
      #pragma unroll
      for (int nt = 0; nt < 4; nt++)
        bf[nt] = *(const bf16x8*)(Bs + (wc + nt * 16 + lrow) * LDK + ks * 32 + lk);
      #pragma unroll
      for (int mt = 0; mt < 4; mt++)
        #pragma unroll
        for (int nt = 0; nt < 4; nt++)
          acc[mt][nt] = MFMA16(af[mt], bf[nt], acc[mt][nt]);
    }
  }

  #pragma unroll
  for (int mt = 0; mt < 4; mt++) {
    const int row0 = bm * 128 + wr + mt * 16 + (lane >> 4) * 4;
    #pragma unroll
    for (int nt = 0; nt < 4; nt++) {
      const int col = bn * 128 + wc + nt * 16 + lrow;
      const float bsv = bias[col];
      #pragma unroll
      for (int r = 0; r < 4; r++) {
        const size_t idx = (size_t)(row0 + r) * N + col;
        const float v = acc[mt][nt][r] + bsv;
        if constexpr (OUT_BF16) {
          outb[idx] = (__bf16)v;
        } else {
          outf[idx] = v + resid[idx];
        }
      }
    }
  }
}

// ---------------- flash attention: per block = (b, head, 64-row q-tile) ----------------
// qkv [B,T,3D] bf16 (Q at +0, K at +D, V at +2D; head hh at cols hh*64..).
// o [B,T,D] bf16. Causal. 4 waves; wave w owns q rows w*16..w*16+15 of the tile.
__global__ __launch_bounds__(256) void flash_kernel(const __bf16* __restrict__ qkv,
                                                    __bf16* __restrict__ o,
                                                    int qt0, int nqt) {
  constexpr int LDK = 72;
  __shared__ __bf16 Qs[64 * LDK];
  __shared__ __bf16 Ks[64 * LDK];
  __shared__ __bf16 Vt[64 * LDK];      // transposed: Vt[dh][krow]
  __shared__ __bf16 Ps[4][16 * LDK];   // per-wave P tile [16 q][64 k]
  const int tid = threadIdx.x, lane = tid & 63, w = tid >> 6;
  const int qt = qt0 + (int)(blockIdx.x % nqt);
  const int hh = (int)(blockIdx.x / nqt) % kH;
  const int b  = (int)(blockIdx.x / nqt) / kH;
  const int lrow = lane & 15, lk = (lane >> 4) * 8;

  // stage Q tile [64][64]
  #pragma unroll
  for (int q = 0; q < 2; q++) {
    const int c = tid + 256 * q;
    const int row = c >> 3, col = (c & 7) * 8;
    bf16x8 v = *(const bf16x8*)(qkv + (size_t)(b * kT + qt * 64 + row) * k3D + hh * kDH + col);
    *(bf16x8*)(Qs + row * LDK + col) = v;
  }
  __syncthreads();
  bf16x8 qf[2];
  qf[0] = *(const bf16x8*)(Qs + (w * 16 + lrow) * LDK + lk);
  qf[1] = *(const bf16x8*)(Qs + (w * 16 + lrow) * LDK + 32 + lk);

  float m_run[4] = {-1e30f, -1e30f, -1e30f, -1e30f};
  float l_run[4] = {0.f, 0.f, 0.f, 0.f};
  f32x4 acc[4] = {};

  for (int kt = 0; kt <= qt; kt++) {
    __syncthreads();  // prior iteration's LDS reads done
    // stage K [krow][dh] and V transposed [dh][krow]
    #pragma unroll
    for (int q = 0; q < 2; q++) {
      const int c = tid + 256 * q;
      const int row = c >> 3, col = (c & 7) * 8;
      const size_t base = (size_t)(b * kT + kt * 64 + row) * k3D + hh * kDH + col;
      bf16x8 kv = *(const bf16x8*)(qkv + base + kD);
      *(bf16x8*)(Ks + row * LDK + col) = kv;
      bf16x8 vv = *(const bf16x8*)(qkv + base + 2 * kD);
      #pragma unroll
      for (int e = 0; e < 8; e++) Vt[(col + e) * LDK + row] = vv[e];
    }
    __syncthreads();

    // S = (Q K^T) * 1/sqrt(DH)
    f32x4 s[4] = {};
    #pragma unroll
    for (int nt = 0; nt < 4; nt++) {
      #pragma unroll
      for (int ks = 0; ks < 2; ks++) {
        bf16x8 kf = *(const bf16x8*)(Ks + (nt * 16 + lrow) * LDK + ks * 32 + lk);
        s[nt] = MFMA16(qf[ks], kf, s[nt]);
      }
    }
    #pragma unroll
    for (int nt = 0; nt < 4; nt++)
      #pragma unroll
      for (int r = 0; r < 4; r++) {
        float v = s[nt][r] * 0.125f;
        if (kt == qt) {
          const int colg = nt * 16 + lrow;
          const int rowg = w * 16 + (lane >> 4) * 4 + r;
          if (colg > rowg) v = -1e30f;
        }
        s[nt][r] = v;
      }

    // online softmax (row stats live in 16-lane groups; rows 4g..4g+3 per group)
    float f[4], psum[4];
    #pragma unroll
    for (int r = 0; r < 4; r++) {
      float mx = fmaxf(fmaxf(s[0][r], s[1][r]), fmaxf(s[2][r], s[3][r]));
      #pragma unroll
      for (int off = 1; off < 16; off <<= 1) mx = fmaxf(mx, __shfl_xor(mx, off));
      const float mnew = fmaxf(m_run[r], mx);
      f[r] = __expf(m_run[r] - mnew);
      m_run[r] = mnew;
      psum[r] = 0.f;
    }
    #pragma unroll
    for (int nt = 0; nt < 4; nt++)
      #pragma unroll
      for (int r = 0; r < 4; r++) {
        const float p = __expf(s[nt][r] - m_run[r]);
        psum[r] += p;
        Ps[w][((lane >> 4) * 4 + r) * LDK + nt * 16 + lrow] = (__bf16)p;
      }
    #pragma unroll
    for (int r = 0; r < 4; r++) {
      float ps = psum[r];
      #pragma unroll
      for (int off = 1; off < 16; off <<= 1) ps += __shfl_xor(ps, off);
      l_run[r] = l_run[r] * f[r] + ps;
    }
    #pragma unroll
    for (int nt = 0; nt < 4; nt++)
      #pragma unroll
      for (int r = 0; r < 4; r++) acc[nt][r] *= f[r];

    asm volatile("s_waitcnt lgkmcnt(0)" ::: "memory");  // P writes visible wave-wide

    // O += P @ V
    bf16x8 pf[2];
    pf[0] = *(const bf16x8*)(&Ps[w][lrow * LDK + lk]);
    pf[1] = *(const bf16x8*)(&Ps[w][lrow * LDK + 32 + lk]);
    #pragma unroll
    for (int nt = 0; nt < 4; nt++) {
      #pragma unroll
      for (int ks = 0; ks < 2; ks++) {
        bf16x8 vf = *(const bf16x8*)(Vt + (nt * 16 + lrow) * LDK + ks * 32 + lk);
        acc[nt] = MFMA16(pf[ks], vf, acc[nt]);
      }
    }
  }

  // epilogue: o = acc / l
  #pragma unroll
  for (int r = 0; r < 4; r++) {
    const int t = qt * 64 + w * 16 + (lane >> 4) * 4 + r;
    const float inv = 1.f / l_run[r];
    #pragma unroll
    for (int nt = 0; nt < 4; nt++)
      o[(size_t)(b * kT + t) * kD + hh * kDH + nt * 16 + lrow] = (__bf16)(acc[nt][r] * inv);
  }
}

// ---------------- layer-2 out-proj, last token only (f32, original W) ----------------
// out4[b][j] = h[b,T-1,j] + bias[j] + sum_k o[b,T-1,k] * W[k][j]
__global__ __launch_bounds__(256) void proj_last_kernel(const __bf16* __restrict__ o,
                                                        const float* __restrict__ W,
                                                        const float* __restrict__ bias,
                                                        const float* __restrict__ h,
                                                        float* __restrict__ out4) {
  const int b = blockIdx.y;
  const int j = blockIdx.x * 256 + threadIdx.x;
  __shared__ float ov[kD];
  const __bf16* orow = o + (size_t)(b * kT + kT - 1) * kD;
  for (int i = threadIdx.x; i < kD; i += 256) ov[i] = (float)orow[i];
  __syncthreads();
  float acc = 0.f;
  #pragma unroll 8
  for (int k = 0; k < kD; k++) acc = fmaf(ov[k], W[(size_t)k * kD + j], acc);
  out4[b * kD + j] = h[(size_t)(b * kT + kT - 1) * kD + j] + bias[j] + acc;
}

// ---------------- head: logits[b][j] = hl[b,:] . head_W[:,j] + head_b[j] ----------------
__global__ __launch_bounds__(256) void head_kernel(const float* __restrict__ hl,
                                                   const float* __restrict__ W,
                                                   const float* __restrict__ hb,
                                                   float* __restrict__ out) {
  const int j = blockIdx.x * 256 + threadIdx.x;
  __shared__ float sh[kB * kD];
  for (int i = threadIdx.x; i < kB * kD; i += 256) sh[i] = hl[i];
  __syncthreads();
  float a0 = 0.f, a1 = 0.f, a2 = 0.f, a3 = 0.f;
  #pragma unroll 8
  for (int k = 0; k < kD; k++) {
    const float wv = W[(size_t)k * kC + j];
    a0 = fmaf(sh[k], wv, a0);
    a1 = fmaf(sh[kD + k], wv, a1);
    a2 = fmaf(sh[2 * kD + k], wv, a2);
    a3 = fmaf(sh[3 * kD + k], wv, a3);
  }
  const float bb = hb[j];
  out[j] = a0 + bb;
  out[kC + j] = a1 + bb;
  out[2 * kC + j] = a2 + bb;
  out[3 * kC + j] = a3 + bb;
}

// ---------------- host ----------------
extern "C" void kernel_launch(void* const* d_in, const int* in_sizes, int n_in,
                              void* d_out, int out_size, void* d_ws, size_t ws_size,
                              hipStream_t stream) {
  const int*   tokens = (const int*)d_in[0];
  const float* embW   = (const float*)d_in[1];
  const float* posW   = (const float*)d_in[2];
  const float* ln_g   = (const float*)d_in[3];
  const float* ln_b   = (const float*)d_in[4];
  const float* qkv_W  = (const float*)d_in[5];
  const float* qkv_b  = (const float*)d_in[6];
  const float* out_W  = (const float*)d_in[7];
  const float* out_b  = (const float*)d_in[8];
  const float* lnf_g  = (const float*)d_in[9];
  const float* lnf_b  = (const float*)d_in[10];
  const float* headW  = (const float*)d_in[11];
  const float* headb  = (const float*)d_in[12];
  float* logits = (float*)d_out;

  char* ws = (char*)d_ws;
  float*  h     = (float*)(ws);                    // [8192][1024] f32   32 MiB
  __bf16* hn    = (__bf16*)(ws + 33554432);        // [8192][1024] bf16  16 MiB
  __bf16* qkv   = (__bf16*)(ws + 50331648);        // [8192][3072] bf16  48 MiB
  __bf16* ob    = (__bf16*)(ws + 100663296);       // [8192][1024] bf16  16 MiB
  __bf16* WqkvT = (__bf16*)(ws + 117440512);       // [2][3072][1024] bf16 12 MiB
  __bf16* WoT   = (__bf16*)(ws + 130023424);       // [1024][1024] bf16 (layer 0)
  float*  hl4   = (float*)(ws + 132120576);        // [4][1024]
  float*  hl    = (float*)(ws + 132136960);        // [4][1024]

  // weights -> bf16 transposed [N][K]
  transpose_w_kernel<<<(kD/32)*(k3D/32), 256, 0, stream>>>(qkv_W, WqkvT, kD, k3D);
  transpose_w_kernel<<<(kD/32)*(k3D/32), 256, 0, stream>>>(qkv_W + (size_t)kD*k3D,
                                                           WqkvT + (size_t)k3D*kD, kD, k3D);
  transpose_w_kernel<<<(kD/32)*(kD/32), 256, 0, stream>>>(out_W, WoT, kD, kD);

  embed_kernel<<<kM, 256, 0, stream>>>(tokens, embW, posW, h);

  // ---- layer 0 ----
  ln_kernel<true><<<kM, 256, 0, stream>>>(h, ln_g, ln_b, hn);
  gemm_bt_kernel<true><<<(kM/128)*(k3D/128), 256, 0, stream>>>(hn, WqkvT, qkv_b,
                                                               nullptr, nullptr, qkv, kM, k3D, kD);
  flash_kernel<<<kB*kH*(kT/64), 256, 0, stream>>>(qkv, ob, 0, kT/64);
  gemm_bt_kernel<false><<<(kM/128)*(kD/128), 256, 0, stream>>>(ob, WoT, out_b,
                                                               h, h, nullptr, kM, kD, kD);

  // ---- layer 1 (only last q-tile of attention + last-token projection needed) ----
  ln_kernel<true><<<kM, 256, 0, stream>>>(h, ln_g + kD, ln_b + kD, hn);
  gemm_bt_kernel<true><<<(kM/128)*(k3D/128), 256, 0, stream>>>(hn, WqkvT + (size_t)k3D*kD,
                                                               qkv_b + k3D, nullptr, nullptr,
                                                               qkv, kM, k3D, kD);
  flash_kernel<<<kB*kH, 256, 0, stream>>>(qkv, ob, kT/64 - 1, 1);
  proj_last_kernel<<<dim3(kD/256, kB), 256, 0, stream>>>(ob, out_W + (size_t)kD*kD,
                                                         out_b + kD, h, hl4);

  ln_kernel<false><<<kB, 256, 0, stream>>>(hl4, lnf_g, lnf_b, hl);
  head_kernel<<<kC/256, 256, 0, stream>>>(hl, headW, headb, logits);
}

// Round 2
// 570.777 us; speedup vs baseline: 1.3361x; 1.3361x over previous
//
#include <hip/hip_runtime.h>

typedef __attribute__((ext_vector_type(8))) __bf16 bf16x8;
typedef __attribute__((ext_vector_type(4))) __bf16 bf16x4;
typedef __attribute__((ext_vector_type(4))) float f32x4;

static constexpr int kB = 4, kT = 2048, kD = 1024, kH = 16, kDH = 64;
static constexpr int kC = 32000, kM = 8192, k3D = 3072;

#define MFMA16(a, b, c) __builtin_amdgcn_mfma_f32_16x16x32_bf16((a), (b), (c), 0, 0, 0)

__device__ __forceinline__ void gload_lds16(const __bf16* g, __bf16* l) {
  __builtin_amdgcn_global_load_lds(
      (const __attribute__((address_space(1))) unsigned int*)(const void*)g,
      (__attribute__((address_space(3))) unsigned int*)(void*)l, 16, 0, 0);
}

// ---------------- embed ----------------
__global__ __launch_bounds__(256) void embed_kernel(const int* __restrict__ tok,
                                                    const float* __restrict__ embW,
                                                    const float* __restrict__ posW,
                                                    float* __restrict__ h) {
  const int row = blockIdx.x;
  const int t = row & (kT - 1);
  const int tk = tok[row];
  const f32x4 e = ((const f32x4*)(embW + (size_t)tk * kD))[threadIdx.x];
  const f32x4 p = ((const f32x4*)(posW + (size_t)t * kD))[threadIdx.x];
  ((f32x4*)(h + (size_t)row * kD))[threadIdx.x] = e + p;
}

// ---------------- LayerNorm (one 256-thr block per row) ----------------
template <bool BF16OUT>
__global__ __launch_bounds__(256) void ln_kernel(const float* __restrict__ x,
                                                 const float* __restrict__ g,
                                                 const float* __restrict__ bb,
                                                 void* __restrict__ outp) {
  const int row = blockIdx.x, tid = threadIdx.x;
  const f32x4 xv = ((const f32x4*)(x + (size_t)row * kD))[tid];
  float s  = xv[0] + xv[1] + xv[2] + xv[3];
  float s2 = xv[0]*xv[0] + xv[1]*xv[1] + xv[2]*xv[2] + xv[3]*xv[3];
  #pragma unroll
  for (int off = 1; off < 64; off <<= 1) {
    s  += __shfl_xor(s, off);
    s2 += __shfl_xor(s2, off);
  }
  __shared__ float red[8];
  const int w = tid >> 6;
  if ((tid & 63) == 0) { red[w*2] = s; red[w*2+1] = s2; }
  __syncthreads();
  s  = red[0] + red[2] + red[4] + red[6];
  s2 = red[1] + red[3] + red[5] + red[7];
  const float mu  = s * (1.f / kD);
  const float var = s2 * (1.f / kD) - mu * mu;
  const float rs  = rsqrtf(var + 1e-5f);
  const f32x4 gv = ((const f32x4*)g)[tid];
  const f32x4 bv = ((const f32x4*)bb)[tid];
  if constexpr (BF16OUT) {
    bf16x4 o;
    #pragma unroll
    for (int i = 0; i < 4; i++) o[i] = (__bf16)((xv[i] - mu) * rs * gv[i] + bv[i]);
    ((bf16x4*)((__bf16*)outp + (size_t)row * kD))[tid] = o;
  } else {
    f32x4 o;
    #pragma unroll
    for (int i = 0; i < 4; i++) o[i] = (xv[i] - mu) * rs * gv[i] + bv[i];
    ((f32x4*)((float*)outp + (size_t)row * kD))[tid] = o;
  }
}

// ---------------- W [K][N] f32 -> WT [N][K] bf16 ----------------
__global__ __launch_bounds__(256) void transpose_w_kernel(const float* __restrict__ W,
                                                          __bf16* __restrict__ WT,
                                                          int K, int N) {
  __shared__ float sh[32][33];
  const int tx = threadIdx.x & 31, ty = threadIdx.x >> 5;
  const int ntile = N >> 5;
  const int c0 = (blockIdx.x % ntile) << 5;
  const int r0 = (blockIdx.x / ntile) << 5;
  #pragma unroll
  for (int i = 0; i < 4; i++) {
    const int r = ty + i * 8;
    sh[r][tx] = W[(size_t)(r0 + r) * N + c0 + tx];
  }
  __syncthreads();
  #pragma unroll
  for (int i = 0; i < 4; i++) {
    const int cc = ty + i * 8;
    WT[(size_t)(c0 + cc) * K + r0 + tx] = (__bf16)sh[tx][cc];
  }
}

// ---------------- GEMM (m97 structure): C = A @ BT^T + bias ----------------
// 128x128 tile, BK=64, linear LDS [128][64], global_load_lds 16B, 4 waves 2x2.
// bm_eff = (blockIdx.x/nbn)*bm_mult + bm_add  (row-tile remap for partial-M launches).
template <bool OUT_BF16>
__global__ __launch_bounds__(256) void gemm_bt_kernel(const __bf16* __restrict__ A,
                                                      const __bf16* __restrict__ BT,
                                                      const float* __restrict__ bias,
                                                      const float* resid,
                                                      float* outf,
                                                      __bf16* outb,
                                                      int N, int K, int ldc,
                                                      int bm_mult, int bm_add) {
  __shared__ __bf16 As[128 * 64];
  __shared__ __bf16 Bs[128 * 64];
  const int tid = threadIdx.x;
  const int lane = tid & 63, w = tid >> 6;
  const int nbn = N >> 7;
  const int bm = (int)(blockIdx.x / nbn) * bm_mult + bm_add;
  const int bn = blockIdx.x % nbn;
  const int wr = (w >> 1) * 64, wc = (w & 1) * 64;
  const int lrow = lane & 15, lk8 = (lane >> 4) * 8;

  const int srow = lane >> 3;          // 0..7 within chunk
  const int scol = (lane & 7) * 8;     // k-element offset
  const __bf16* gA = A + (size_t)(bm * 128) * K;
  const __bf16* gB = BT + (size_t)(bn * 128) * K;

  f32x4 acc[4][4] = {};

  for (int k0 = 0; k0 < K; k0 += 64) {
    __syncthreads();   // previous MFMA reads done before overwrite
    #pragma unroll
    for (int i = 0; i < 4; i++) {
      const int c = w * 4 + i;                 // chunk 0..15 (8 rows each)
      const int row = c * 8 + srow;
      gload_lds16(gA + (size_t)row * K + k0 + scol, As + c * 512);
      gload_lds16(gB + (size_t)row * K + k0 + scol, Bs + c * 512);
    }
    __syncthreads();   // loads landed (vmcnt drained by barrier)
    #pragma unroll
    for (int ks = 0; ks < 2; ks++) {
      bf16x8 af[4], bf[4];
      #pragma unroll
      for (int mt = 0; mt < 4; mt++)
        af[mt] = *(const bf16x8*)(As + (wr + mt * 16 + lrow) * 64 + ks * 32 + lk8);
      #pragma unroll
      for (int nt = 0; nt < 4; nt++)
        bf[nt] = *(const bf16x8*)(Bs + (wc + nt * 16 + lrow) * 64 + ks * 32 + lk8);
      #pragma unroll
      for (int mt = 0; mt < 4; mt++)
        #pragma unroll
        for (int nt = 0; nt < 4; nt++)
          acc[mt][nt] = MFMA16(af[mt], bf[nt], acc[mt][nt]);
    }
  }

  #pragma unroll
  for (int mt = 0; mt < 4; mt++) {
    const int row0 = bm * 128 + wr + mt * 16 + (lane >> 4) * 4;
    #pragma unroll
    for (int nt = 0; nt < 4; nt++) {
      const int col = bn * 128 + wc + nt * 16 + lrow;
      const float bsv = bias[col];
      #pragma unroll
      for (int r = 0; r < 4; r++) {
        const size_t idx = (size_t)(row0 + r) * ldc + col;
        const float v = acc[mt][nt][r] + bsv;
        if constexpr (OUT_BF16) {
          outb[idx] = (__bf16)v;
        } else {
          outf[idx] = v + resid[idx];
        }
      }
    }
  }
}

// ---------------- flash attention ----------------
// MODE 0: paired causal tiles {sub, 2*nsub-1-sub} per block (uniform 33 iters), writes o.
// MODE 1: qt=31 fixed, k-chunk sub of nsub, writes unnormalized f32 partials + (m,l).
// exp2-domain softmax. Vt XOR-swizzled on k: k ^= ((d>>3)&7)<<3 (both write & read).
template <int MODE>
__global__ __launch_bounds__(256) void flash_kernel(const __bf16* __restrict__ qkv,
                                                    __bf16* __restrict__ o,
                                                    float* __restrict__ part_acc,
                                                    float* __restrict__ part_ml,
                                                    int nsub) {
  constexpr int LDK = 72;
  constexpr float SC = 0.18033688011112042f;  // (1/8) * log2(e)
  __shared__ __bf16 Qs[64 * LDK];
  __shared__ __bf16 Ks[64 * LDK];
  __shared__ __bf16 Vt[64 * LDK];
  __shared__ __bf16 Ps[4][16 * LDK];
  const int tid = threadIdx.x, lane = tid & 63, w = tid >> 6;
  const int sub = (int)(blockIdx.x % nsub);
  const int bh = (int)(blockIdx.x / nsub);
  const int b = bh >> 4, hh = bh & 15;
  const int lrow = lane & 15, lk8 = (lane >> 4) * 8;
  const int NSUB = (MODE == 0) ? 2 : 1;

  for (int s = 0; s < NSUB; s++) {
    int qt, ktlo, kthi;
    if constexpr (MODE == 0) {
      qt = (s == 0) ? sub : (2 * nsub - 1 - sub);
      ktlo = 0; kthi = qt + 1;
    } else {
      qt = 31;
      ktlo = sub * (32 / 8); kthi = ktlo + 4;   // nsub == 8 chunks of 4
    }

    // stage Q tile [64][64]
    #pragma unroll
    for (int q = 0; q < 2; q++) {
      const int c = tid + 256 * q;
      const int row = c >> 3, col = (c & 7) * 8;
      bf16x8 v = *(const bf16x8*)(qkv + (size_t)(b * kT + qt * 64 + row) * k3D + hh * kDH + col);
      *(bf16x8*)(Qs + row * LDK + col) = v;
    }
    __syncthreads();
    bf16x8 qf[2];
    qf[0] = *(const bf16x8*)(Qs + (w * 16 + lrow) * LDK + lk8);
    qf[1] = *(const bf16x8*)(Qs + (w * 16 + lrow) * LDK + 32 + lk8);

    float m_run[4] = {-1e30f, -1e30f, -1e30f, -1e30f};
    float l_run[4] = {0.f, 0.f, 0.f, 0.f};
    f32x4 acc[4] = {};

    for (int kt = ktlo; kt < kthi; kt++) {
      __syncthreads();  // prior LDS reads complete before restage
      #pragma unroll
      for (int q = 0; q < 2; q++) {
        const int c = tid + 256 * q;
        const int row = c >> 3, col = (c & 7) * 8;
        const size_t base = (size_t)(b * kT + kt * 64 + row) * k3D + hh * kDH + col;
        bf16x8 kv = *(const bf16x8*)(qkv + base + kD);
        *(bf16x8*)(Ks + row * LDK + col) = kv;
        bf16x8 vv = *(const bf16x8*)(qkv + base + 2 * kD);
        #pragma unroll
        for (int e = 0; e < 8; e++) {
          const int d = col + e;
          Vt[d * LDK + (row ^ (((d >> 3) & 7) << 3))] = vv[e];
        }
      }
      __syncthreads();

      // S = (Q K^T) * SC  (log2 domain)
      f32x4 sv[4] = {};
      #pragma unroll
      for (int nt = 0; nt < 4; nt++) {
        #pragma unroll
        for (int ks = 0; ks < 2; ks++) {
          bf16x8 kf = *(const bf16x8*)(Ks + (nt * 16 + lrow) * LDK + ks * 32 + lk8);
          sv[nt] = MFMA16(qf[ks], kf, sv[nt]);
        }
      }
      #pragma unroll
      for (int nt = 0; nt < 4; nt++)
        #pragma unroll
        for (int r = 0; r < 4; r++) {
          float v = sv[nt][r] * SC;
          if (kt == qt) {
            const int colg = nt * 16 + lrow;
            const int rowg = w * 16 + (lane >> 4) * 4 + r;
            if (colg > rowg) v = -1e30f;
          }
          sv[nt][r] = v;
        }

      float f[4], psum[4];
      #pragma unroll
      for (int r = 0; r < 4; r++) {
        float mx = fmaxf(fmaxf(sv[0][r], sv[1][r]), fmaxf(sv[2][r], sv[3][r]));
        #pragma unroll
        for (int off = 1; off < 16; off <<= 1) mx = fmaxf(mx, __shfl_xor(mx, off));
        const float mnew = fmaxf(m_run[r], mx);
        f[r] = exp2f(m_run[r] - mnew);
        m_run[r] = mnew;
        psum[r] = 0.f;
      }
      #pragma unroll
      for (int nt = 0; nt < 4; nt++)
        #pragma unroll
        for (int r = 0; r < 4; r++) {
          const float p = exp2f(sv[nt][r] - m_run[r]);
          psum[r] += p;
          Ps[w][((lane >> 4) * 4 + r) * LDK + nt * 16 + lrow] = (__bf16)p;
        }
      #pragma unroll
      for (int r = 0; r < 4; r++) {
        float ps = psum[r];
        #pragma unroll
        for (int off = 1; off < 16; off <<= 1) ps += __shfl_xor(ps, off);
        l_run[r] = l_run[r] * f[r] + ps;
      }
      #pragma unroll
      for (int nt = 0; nt < 4; nt++)
        #pragma unroll
        for (int r = 0; r < 4; r++) acc[nt][r] *= f[r];

      asm volatile("s_waitcnt lgkmcnt(0)" ::: "memory");

      bf16x8 pf[2];
      pf[0] = *(const bf16x8*)(&Ps[w][lrow * LDK + lk8]);
      pf[1] = *(const bf16x8*)(&Ps[w][lrow * LDK + 32 + lk8]);
      #pragma unroll
      for (int nt = 0; nt < 4; nt++) {
        const int d = nt * 16 + lrow;
        const int swz = ((d >> 3) & 7) << 3;
        #pragma unroll
        for (int ks = 0; ks < 2; ks++) {
          bf16x8 vf = *(const bf16x8*)(Vt + d * LDK + ((ks * 32 + lk8) ^ swz));
          acc[nt] = MFMA16(pf[ks], vf, acc[nt]);
        }
      }
    }

    if constexpr (MODE == 0) {
      #pragma unroll
      for (int r = 0; r < 4; r++) {
        const int t = qt * 64 + w * 16 + (lane >> 4) * 4 + r;
        const float inv = 1.f / l_run[r];
        #pragma unroll
        for (int nt = 0; nt < 4; nt++)
          o[(size_t)(b * kT + t) * kD + hh * kDH + nt * 16 + lrow] = (__bf16)(acc[nt][r] * inv);
      }
    } else {
      const int tile = bh * nsub + sub;
      #pragma unroll
      for (int r = 0; r < 4; r++) {
        const int row = w * 16 + (lane >> 4) * 4 + r;
        #pragma unroll
        for (int nt = 0; nt < 4; nt++)
          part_acc[(size_t)tile * 4096 + row * 64 + nt * 16 + lrow] = acc[nt][r];
        if (lrow == 0) {
          part_ml[tile * 128 + row] = m_run[r];
          part_ml[tile * 128 + 64 + row] = l_run[r];
        }
      }
    }
  }
}

// ---------------- merge k-split flash partials (qt=31) ----------------
__global__ __launch_bounds__(256) void flash_merge_kernel(const float* __restrict__ part_acc,
                                                          const float* __restrict__ part_ml,
                                                          __bf16* __restrict__ o) {
  const int bh = blockIdx.x, b = bh >> 4, hh = bh & 15;
  for (int e = threadIdx.x; e < 4096; e += 256) {
    const int row = e >> 6, d = e & 63;
    float mstar = -1e30f;
    #pragma unroll
    for (int kc = 0; kc < 8; kc++)
      mstar = fmaxf(mstar, part_ml[(bh * 8 + kc) * 128 + row]);
    float lstar = 0.f, osum = 0.f;
    #pragma unroll
    for (int kc = 0; kc < 8; kc++) {
      const float wgt = exp2f(part_ml[(bh * 8 + kc) * 128 + row] - mstar);
      lstar += wgt * part_ml[(bh * 8 + kc) * 128 + 64 + row];
      osum  += wgt * part_acc[(size_t)(bh * 8 + kc) * 4096 + e];
    }
    o[(size_t)(b * kT + 1984 + row) * kD + hh * 64 + d] = (__bf16)(osum / lstar);
  }
}

// ---------------- layer-2 out-proj, last token only ----------------
__global__ __launch_bounds__(256) void proj_last_kernel(const __bf16* __restrict__ o,
                                                        const float* __restrict__ W,
                                                        const float* __restrict__ bias,
                                                        const float* __restrict__ h,
                                                        float* __restrict__ out4) {
  const int b = blockIdx.y;
  const int j = blockIdx.x * 256 + threadIdx.x;
  __shared__ float ov[kD];
  const __bf16* orow = o + (size_t)(b * kT + kT - 1) * kD;
  for (int i = threadIdx.x; i < kD; i += 256) ov[i] = (float)orow[i];
  __syncthreads();
  float acc = 0.f;
  #pragma unroll 8
  for (int k = 0; k < kD; k++) acc = fmaf(ov[k], W[(size_t)k * kD + j], acc);
  out4[b * kD + j] = h[(size_t)(b * kT + kT - 1) * kD + j] + bias[j] + acc;
}

// ---------------- head ----------------
__global__ __launch_bounds__(256) void head_kernel(const float* __restrict__ hl,
                                                   const float* __restrict__ W,
                                                   const float* __restrict__ hb,
                                                   float* __restrict__ out) {
  const int j = blockIdx.x * 256 + threadIdx.x;
  __shared__ float sh[kB * kD];
  for (int i = threadIdx.x; i < kB * kD; i += 256) sh[i] = hl[i];
  __syncthreads();
  float a0 = 0.f, a1 = 0.f, a2 = 0.f, a3 = 0.f;
  #pragma unroll 8
  for (int k = 0; k < kD; k++) {
    const float wv = W[(size_t)k * kC + j];
    a0 = fmaf(sh[k], wv, a0);
    a1 = fmaf(sh[kD + k], wv, a1);
    a2 = fmaf(sh[2 * kD + k], wv, a2);
    a3 = fmaf(sh[3 * kD + k], wv, a3);
  }
  const float bb = hb[j];
  out[j] = a0 + bb;
  out[kC + j] = a1 + bb;
  out[2 * kC + j] = a2 + bb;
  out[3 * kC + j] = a3 + bb;
}

// ---------------- host ----------------
extern "C" void kernel_launch(void* const* d_in, const int* in_sizes, int n_in,
                              void* d_out, int out_size, void* d_ws, size_t ws_size,
                              hipStream_t stream) {
  const int*   tokens = (const int*)d_in[0];
  const float* embW   = (const float*)d_in[1];
  const float* posW   = (const float*)d_in[2];
  const float* ln_g   = (const float*)d_in[3];
  const float* ln_b   = (const float*)d_in[4];
  const float* qkv_W  = (const float*)d_in[5];
  const float* qkv_b  = (const float*)d_in[6];
  const float* out_W  = (const float*)d_in[7];
  const float* out_b  = (const float*)d_in[8];
  const float* lnf_g  = (const float*)d_in[9];
  const float* lnf_b  = (const float*)d_in[10];
  const float* headW  = (const float*)d_in[11];
  const float* headb  = (const float*)d_in[12];
  float* logits = (float*)d_out;

  char* ws = (char*)d_ws;
  float*  h     = (float*)(ws);                    // [8192][1024] f32   32 MiB
  __bf16* hn    = (__bf16*)(ws + 33554432);        // [8192][1024] bf16  16 MiB
  __bf16* qkv   = (__bf16*)(ws + 50331648);        // [8192][3072] bf16  48 MiB
  __bf16* ob    = (__bf16*)(ws + 100663296);       // [8192][1024] bf16  16 MiB
  __bf16* WqkvT = (__bf16*)(ws + 117440512);       // [2][3072][1024] bf16 12 MiB
  __bf16* WoT   = (__bf16*)(ws + 130023424);       // [1024][1024] bf16 (layer 0)
  float*  hl4   = (float*)(ws + 132120576);        // [4][1024]
  float*  hl    = (float*)(ws + 132136960);        // [4][1024]
  // flash-l1 partials reuse the hn region (hn is dead once l1 qkv GEMMs issued)
  float* part_acc = (float*)(ws + 33554432);       // 512 tiles * 4096 f32 = 8 MiB
  float* part_ml  = (float*)(ws + 33554432 + 8388608);  // 512 * 128 f32

  transpose_w_kernel<<<(kD/32)*(k3D/32), 256, 0, stream>>>(qkv_W, WqkvT, kD, k3D);
  transpose_w_kernel<<<(kD/32)*(k3D/32), 256, 0, stream>>>(qkv_W + (size_t)kD*k3D,
                                                           WqkvT + (size_t)k3D*kD, kD, k3D);
  transpose_w_kernel<<<(kD/32)*(kD/32), 256, 0, stream>>>(out_W, WoT, kD, kD);

  embed_kernel<<<kM, 256, 0, stream>>>(tokens, embW, posW, h);

  // ---- layer 0 ----
  ln_kernel<true><<<kM, 256, 0, stream>>>(h, ln_g, ln_b, hn);
  gemm_bt_kernel<true><<<(kM/128)*(k3D/128), 256, 0, stream>>>(
      hn, WqkvT, qkv_b, nullptr, nullptr, qkv, k3D, kD, k3D, 1, 0);
  flash_kernel<0><<<kB*kH*16, 256, 0, stream>>>(qkv, ob, nullptr, nullptr, 16);
  gemm_bt_kernel<false><<<(kM/128)*(kD/128), 256, 0, stream>>>(
      ob, WoT, out_b, h, h, nullptr, kD, kD, kD, 1, 0);

  // ---- layer 1 ----
  ln_kernel<true><<<kM, 256, 0, stream>>>(h, ln_g + kD, ln_b + kD, hn);
  // K,V for all tokens (cols 1024..3071)
  gemm_bt_kernel<true><<<(kM/128)*(2048/128), 256, 0, stream>>>(
      hn, WqkvT + (size_t)k3D*kD + (size_t)kD*kD, qkv_b + k3D + kD,
      nullptr, nullptr, qkv + kD, 2048, kD, k3D, 1, 0);
  // Q only for each batch's last 128 rows: bm_eff = bidx*16 + 15
  gemm_bt_kernel<true><<<kB*(kD/128), 256, 0, stream>>>(
      hn, WqkvT + (size_t)k3D*kD, qkv_b + k3D,
      nullptr, nullptr, qkv, kD, kD, k3D, 16, 15);
  // k-split flash for qt=31 (8 chunks of 4 kv-tiles) + merge
  flash_kernel<1><<<kB*kH*8, 256, 0, stream>>>(qkv, nullptr, part_acc, part_ml, 8);
  flash_merge_kernel<<<kB*kH, 256, 0, stream>>>(part_acc, part_ml, ob);
  proj_last_kernel<<<dim3(kD/256, kB), 256, 0, stream>>>(ob, out_W + (size_t)kD*kD,
                                                         out_b + kD, h, hl4);

  ln_kernel<false><<<kB, 256, 0, stream>>>(hl4, lnf_g, lnf_b, hl);
  head_kernel<<<kC/256, 256, 0, stream>>>(hl, headW, headb, logits);
}

// Round 3
// 535.105 us; speedup vs baseline: 1.4251x; 1.0667x over previous
//
#include <hip/hip_runtime.h>

typedef __attribute__((ext_vector_type(8))) __bf16 bf16x8;
typedef __attribute__((ext_vector_type(4))) __bf16 bf16x4;
typedef __attribute__((ext_vector_type(4))) float f32x4;
typedef unsigned long long ull;

static constexpr int kB = 4, kT = 2048, kD = 1024, kH = 16;
static constexpr int kC = 32000, kM = 8192, k3D = 3072, kQK = 2048;

#define MFMA16(a, b, c) __builtin_amdgcn_mfma_f32_16x16x32_bf16((a), (b), (c), 0, 0, 0)

__device__ __forceinline__ void gload_lds16(const __bf16* g, __bf16* l) {
  __builtin_amdgcn_global_load_lds(
      (const __attribute__((address_space(1))) unsigned int*)(const void*)g,
      (__attribute__((address_space(3))) unsigned int*)(void*)l, 16, 0, 0);
}

// ---------------- embed ----------------
__global__ __launch_bounds__(256) void embed_kernel(const int* __restrict__ tok,
                                                    const float* __restrict__ embW,
                                                    const float* __restrict__ posW,
                                                    float* __restrict__ h) {
  const int row = blockIdx.x;
  const int t = row & (kT - 1);
  const int tk = tok[row];
  const f32x4 e = ((const f32x4*)(embW + (size_t)tk * kD))[threadIdx.x];
  const f32x4 p = ((const f32x4*)(posW + (size_t)t * kD))[threadIdx.x];
  ((f32x4*)(h + (size_t)row * kD))[threadIdx.x] = e + p;
}

// ---------------- LayerNorm ----------------
template <bool BF16OUT>
__global__ __launch_bounds__(256) void ln_kernel(const float* __restrict__ x,
                                                 const float* __restrict__ g,
                                                 const float* __restrict__ bb,
                                                 void* __restrict__ outp) {
  const int row = blockIdx.x, tid = threadIdx.x;
  const f32x4 xv = ((const f32x4*)(x + (size_t)row * kD))[tid];
  float s  = xv[0] + xv[1] + xv[2] + xv[3];
  float s2 = xv[0]*xv[0] + xv[1]*xv[1] + xv[2]*xv[2] + xv[3]*xv[3];
  #pragma unroll
  for (int off = 1; off < 64; off <<= 1) {
    s  += __shfl_xor(s, off);
    s2 += __shfl_xor(s2, off);
  }
  __shared__ float red[8];
  const int w = tid >> 6;
  if ((tid & 63) == 0) { red[w*2] = s; red[w*2+1] = s2; }
  __syncthreads();
  s  = red[0] + red[2] + red[4] + red[6];
  s2 = red[1] + red[3] + red[5] + red[7];
  const float mu  = s * (1.f / kD);
  const float var = s2 * (1.f / kD) - mu * mu;
  const float rs  = rsqrtf(var + 1e-5f);
  const f32x4 gv = ((const f32x4*)g)[tid];
  const f32x4 bv = ((const f32x4*)bb)[tid];
  if constexpr (BF16OUT) {
    bf16x4 o;
    #pragma unroll
    for (int i = 0; i < 4; i++) o[i] = (__bf16)((xv[i] - mu) * rs * gv[i] + bv[i]);
    ((bf16x4*)((__bf16*)outp + (size_t)row * kD))[tid] = o;
  } else {
    f32x4 o;
    #pragma unroll
    for (int i = 0; i < 4; i++) o[i] = (xv[i] - mu) * rs * gv[i] + bv[i];
    ((f32x4*)((float*)outp + (size_t)row * kD))[tid] = o;
  }
}

// ---------------- W [K][N] f32 -> WT [N][K] bf16 ----------------
__global__ __launch_bounds__(256) void transpose_w_kernel(const float* __restrict__ W,
                                                          __bf16* __restrict__ WT,
                                                          int K, int N) {
  __shared__ float sh[32][33];
  const int tx = threadIdx.x & 31, ty = threadIdx.x >> 5;
  const int ntile = N >> 5;
  const int c0 = (blockIdx.x % ntile) << 5;
  const int r0 = (blockIdx.x / ntile) << 5;
  #pragma unroll
  for (int i = 0; i < 4; i++) {
    const int r = ty + i * 8;
    sh[r][tx] = W[(size_t)(r0 + r) * N + c0 + tx];
  }
  __syncthreads();
  #pragma unroll
  for (int i = 0; i < 4; i++) {
    const int cc = ty + i * 8;
    WT[(size_t)(c0 + cc) * K + r0 + tx] = (__bf16)sh[tx][cc];
  }
}

// ---------------- GEMM (m97 structure): C = A @ BT^T + bias ----------------
// 128x128 tile, BK=64, linear LDS, global_load_lds 16B, XCD-swizzled grid.
// Columns >= vt_c0 (when vtp != null) are V: written transposed to vtp[bh][d][t].
template <bool OUT_BF16>
__global__ __launch_bounds__(256) void gemm_bt_kernel(const __bf16* __restrict__ A,
                                                      const __bf16* __restrict__ BT,
                                                      const float* __restrict__ bias,
                                                      const float* resid,
                                                      float* outf,
                                                      __bf16* outb,
                                                      __bf16* vtp,
                                                      int N, int K, int ldc, int vt_c0,
                                                      int bm_mult, int bm_add) {
  __shared__ __bf16 As[128 * 64];
  __shared__ __bf16 Bs[128 * 64];
  const int tid = threadIdx.x;
  const int lane = tid & 63, w = tid >> 6;
  int wg = (int)blockIdx.x;
  const int nwg = gridDim.x;
  wg = (wg & 7) * (nwg >> 3) + (wg >> 3);      // bijective XCD swizzle (nwg%8==0)
  const int nbn = N >> 7;
  const int bm = (wg / nbn) * bm_mult + bm_add;
  const int bn = wg % nbn;
  const int wr = (w >> 1) * 64, wc = (w & 1) * 64;
  const int lrow = lane & 15, lk8 = (lane >> 4) * 8;

  const int srow = lane >> 3;
  const int scol = (lane & 7) * 8;
  const __bf16* gA = A + (size_t)(bm * 128) * K;
  const __bf16* gB = BT + (size_t)(bn * 128) * K;

  f32x4 acc[4][4] = {};

  for (int k0 = 0; k0 < K; k0 += 64) {
    __syncthreads();
    #pragma unroll
    for (int i = 0; i < 4; i++) {
      const int c = w * 4 + i;
      const int row = c * 8 + srow;
      gload_lds16(gA + (size_t)row * K + k0 + scol, As + c * 512);
      gload_lds16(gB + (size_t)row * K + k0 + scol, Bs + c * 512);
    }
    __syncthreads();
    #pragma unroll
    for (int ks = 0; ks < 2; ks++) {
      bf16x8 af[4], bf[4];
      #pragma unroll
      for (int mt = 0; mt < 4; mt++)
        af[mt] = *(const bf16x8*)(As + (wr + mt * 16 + lrow) * 64 + ks * 32 + lk8);
      #pragma unroll
      for (int nt = 0; nt < 4; nt++)
        bf[nt] = *(const bf16x8*)(Bs + (wc + nt * 16 + lrow) * 64 + ks * 32 + lk8);
      #pragma unroll
      for (int mt = 0; mt < 4; mt++)
        #pragma unroll
        for (int nt = 0; nt < 4; nt++)
          acc[mt][nt] = MFMA16(af[mt], bf[nt], acc[mt][nt]);
    }
  }

  #pragma unroll
  for (int mt = 0; mt < 4; mt++) {
    const int row0 = bm * 128 + wr + mt * 16 + (lane >> 4) * 4;
    #pragma unroll
    for (int nt = 0; nt < 4; nt++) {
      const int col = bn * 128 + wc + nt * 16 + lrow;
      const float bsv = bias[col];
      if (vtp && col >= vt_c0) {
        const int vd = col - vt_c0;                 // h*64 + d
        const int bb_ = row0 >> 11, t = row0 & (kT - 1);
        bf16x4 pk;
        #pragma unroll
        for (int r = 0; r < 4; r++) pk[r] = (__bf16)(acc[mt][nt][r] + bsv);
        *(bf16x4*)(vtp + ((size_t)((bb_ << 4) + (vd >> 6)) * 64 + (vd & 63)) * kT + t) = pk;
      } else {
        #pragma unroll
        for (int r = 0; r < 4; r++) {
          const size_t idx = (size_t)(row0 + r) * ldc + col;
          const float v = acc[mt][nt][r] + bsv;
          if constexpr (OUT_BF16) {
            outb[idx] = (__bf16)v;
          } else {
            outf[idx] = v + resid[idx];
          }
        }
      }
    }
  }
}

// ---------------- flash attention, swapped QK^T, in-register P ----------------
// qkv [B*T][2048] bf16 = Q|K. vtg [64 bh][64 d][2048 t] bf16.
// MODE 0: paired causal q-tiles {sub, 2*nsub-1-sub}; MODE 1: qt=31, k-chunk split.
// Tiles staged via global_load_lds, source-XOR swizzle (slot^row&7), swizzled b128 reads.
template <int MODE>
__global__ __launch_bounds__(256) void flash_kernel(const __bf16* __restrict__ qkv,
                                                    const __bf16* __restrict__ vtg,
                                                    __bf16* __restrict__ o,
                                                    float* __restrict__ part_acc,
                                                    float* __restrict__ part_ml,
                                                    int nsub) {
  constexpr float SC = 0.18033688011112042f;  // (1/8)*log2(e)
  __shared__ __bf16 Qs[64 * 64];
  __shared__ __bf16 Ks[64 * 64];
  __shared__ __bf16 Vs[64 * 64];
  const int tid = threadIdx.x, lane = tid & 63, w = tid >> 6;
  int wg = (int)blockIdx.x;
  const int nwg = gridDim.x;
  wg = (wg & 7) * (nwg >> 3) + (wg >> 3);
  const int sub = wg % nsub, bh = wg / nsub;
  const int b = bh >> 4, hh = bh & 15;
  const int g = lane >> 4, qown = lane & 15;
  const int sslot = (lane & 7) ^ ((lane >> 3) & 7);   // inverse-swizzled source slot
  const int swz = (qown & 7) << 3;                     // read-side XOR (elements)
  const size_t row0 = (size_t)b * kT;
  const int NS = (MODE == 0) ? 2 : 1;

  for (int s = 0; s < NS; s++) {
    int qt, ktlo, kthi;
    if constexpr (MODE == 0) {
      qt = s ? (2 * nsub - 1 - sub) : sub;
      ktlo = 0; kthi = qt + 1;
    } else {
      qt = 31; ktlo = sub * 4; kthi = ktlo + 4;
    }

    __syncthreads();   // prior reads (previous s) done
    #pragma unroll
    for (int j = 0; j < 2; j++) {
      const int r = w * 16 + j * 8 + (lane >> 3);
      gload_lds16(qkv + (row0 + qt * 64 + r) * kQK + hh * 64 + sslot * 8,
                  Qs + (w * 16 + j * 8) * 64);
    }
    __syncthreads();   // Q landed
    bf16x8 qf[2];
    #pragma unroll
    for (int ks = 0; ks < 2; ks++) {
      bf16x8 qr = *(const bf16x8*)(Qs + (w * 16 + qown) * 64 + ((ks * 32 + 8 * g) ^ swz));
      #pragma unroll
      for (int i = 0; i < 8; i++) qf[ks][i] = (__bf16)((float)qr[i] * SC);
    }

    float m_run = -1e30f, l_run = 0.f;
    f32x4 acc[4] = {};

    for (int kt = ktlo; kt < kthi; kt++) {
      __syncthreads();   // prior tile reads done
      #pragma unroll
      for (int j = 0; j < 2; j++) {
        const int r = w * 16 + j * 8 + (lane >> 3);
        gload_lds16(qkv + (row0 + kt * 64 + r) * kQK + 1024 + hh * 64 + sslot * 8,
                    Ks + (w * 16 + j * 8) * 64);
        gload_lds16(vtg + ((size_t)bh * 64 + r) * kT + kt * 64 + sslot * 8,
                    Vs + (w * 16 + j * 8) * 64);
      }
      __syncthreads();   // K,V landed

      // S^T tile: thread holds S[k = nt*16+4g+r][q = w*16+qown]
      f32x4 sv[4] = {};
      #pragma unroll
      for (int nt = 0; nt < 4; nt++) {
        const int kr = nt * 16 + qown;
        #pragma unroll
        for (int ks = 0; ks < 2; ks++) {
          bf16x8 kf = *(const bf16x8*)(Ks + kr * 64 + ((ks * 32 + 8 * g) ^ swz));
          sv[nt] = MFMA16(kf, qf[ks], sv[nt]);
        }
      }
      if (kt == qt) {   // wave-uniform causal mask on the diagonal tile
        #pragma unroll
        for (int nt = 0; nt < 4; nt++)
          #pragma unroll
          for (int r = 0; r < 4; r++)
            if (nt * 16 + 4 * g + r > w * 16 + qown) sv[nt][r] = -1e30f;
      }

      // per-lane softmax (one q-row; partials across the 4 lane-groups)
      float mx = -1e30f;
      #pragma unroll
      for (int nt = 0; nt < 4; nt++)
        #pragma unroll
        for (int r = 0; r < 4; r++) mx = fmaxf(mx, sv[nt][r]);
      mx = fmaxf(mx, __shfl_xor(mx, 16));
      mx = fmaxf(mx, __shfl_xor(mx, 32));
      const float mnew = fmaxf(m_run, mx);
      const float fsc = exp2f(m_run - mnew);
      m_run = mnew;
      float ps = 0.f;
      ull quad[4];
      #pragma unroll
      for (int nt = 0; nt < 4; nt++) {
        union { bf16x4 v; ull u; } qd;
        #pragma unroll
        for (int r = 0; r < 4; r++) {
          const float p = exp2f(sv[nt][r] - mnew);
          ps += p;
          qd.v[r] = (__bf16)p;
        }
        quad[nt] = qd.u;
      }
      ps += __shfl_xor(ps, 16);
      ps += __shfl_xor(ps, 32);
      l_run = l_run * fsc + ps;

      float fr[4];
      #pragma unroll
      for (int r = 0; r < 4; r++) fr[r] = __shfl(fsc, 20 * g + r);
      #pragma unroll
      for (int nt = 0; nt < 4; nt++)
        #pragma unroll
        for (int r = 0; r < 4; r++) acc[nt][r] *= fr[r];

      // assemble PV A-fragment: lane needs P[q=qown][k = ks*32 + 8g + i]
      bf16x8 pf[2];
      #pragma unroll
      for (int ks = 0; ks < 2; ks++) {
        const int src = (g & 1) * 32 + qown;
        const ull t0 = __shfl(quad[2 * ks],     src);
        const ull t1 = __shfl(quad[2 * ks + 1], src);
        const ull lo = (g & 2) ? t1 : t0;
        const ull t2 = __shfl(quad[2 * ks],     src + 16);
        const ull t3 = __shfl(quad[2 * ks + 1], src + 16);
        const ull hi = (g & 2) ? t3 : t2;
        union { ull u[2]; bf16x8 v; } pk;
        pk.u[0] = lo; pk.u[1] = hi;
        pf[ks] = pk.v;
      }

      #pragma unroll
      for (int nt = 0; nt < 4; nt++) {
        const int vr = nt * 16 + qown;
        #pragma unroll
        for (int ks = 0; ks < 2; ks++) {
          bf16x8 vf = *(const bf16x8*)(Vs + vr * 64 + ((ks * 32 + 8 * g) ^ swz));
          acc[nt] = MFMA16(pf[ks], vf, acc[nt]);
        }
      }
    }  // kt

    if constexpr (MODE == 0) {
      const float li = 1.f / l_run;
      float lr[4];
      #pragma unroll
      for (int r = 0; r < 4; r++) lr[r] = __shfl(li, 20 * g + r);
      #pragma unroll
      for (int r = 0; r < 4; r++) {
        const int t = qt * 64 + w * 16 + 4 * g + r;
        #pragma unroll
        for (int nt = 0; nt < 4; nt++)
          o[(row0 + t) * kD + hh * 64 + nt * 16 + qown] = (__bf16)(acc[nt][r] * lr[r]);
      }
    } else {
      const int tile = bh * nsub + sub;
      #pragma unroll
      for (int r = 0; r < 4; r++) {
        const int rr = w * 16 + 4 * g + r;
        #pragma unroll
        for (int nt = 0; nt < 4; nt++)
          part_acc[(size_t)tile * 4096 + rr * 64 + nt * 16 + qown] = acc[nt][r];
      }
      if (g == 0) {
        part_ml[tile * 128 + w * 16 + qown] = m_run;
        part_ml[tile * 128 + 64 + w * 16 + qown] = l_run;
      }
    }
  }  // s
}

// ---------------- merge k-split flash partials (qt=31) ----------------
__global__ __launch_bounds__(256) void flash_merge_kernel(const float* __restrict__ part_acc,
                                                          const float* __restrict__ part_ml,
                                                          __bf16* __restrict__ o) {
  const int bh = blockIdx.x, b = bh >> 4, hh = bh & 15;
  for (int e = threadIdx.x; e < 4096; e += 256) {
    const int row = e >> 6, d = e & 63;
    float mstar = -1e30f;
    #pragma unroll
    for (int kc = 0; kc < 8; kc++)
      mstar = fmaxf(mstar, part_ml[(bh * 8 + kc) * 128 + row]);
    float lstar = 0.f, osum = 0.f;
    #pragma unroll
    for (int kc = 0; kc < 8; kc++) {
      const float wgt = exp2f(part_ml[(bh * 8 + kc) * 128 + row] - mstar);
      lstar += wgt * part_ml[(bh * 8 + kc) * 128 + 64 + row];
      osum  += wgt * part_acc[(size_t)(bh * 8 + kc) * 4096 + e];
    }
    o[(size_t)(b * kT + 1984 + row) * kD + hh * 64 + d] = (__bf16)(osum / lstar);
  }
}

// ---------------- layer-2 out-proj, last token only ----------------
__global__ __launch_bounds__(256) void proj_last_kernel(const __bf16* __restrict__ o,
                                                        const float* __restrict__ W,
                                                        const float* __restrict__ bias,
                                                        const float* __restrict__ h,
                                                        float* __restrict__ out4) {
  const int b = blockIdx.y;
  const int j = blockIdx.x * 256 + threadIdx.x;
  __shared__ float ov[kD];
  const __bf16* orow = o + (size_t)(b * kT + kT - 1) * kD;
  for (int i = threadIdx.x; i < kD; i += 256) ov[i] = (float)orow[i];
  __syncthreads();
  float acc = 0.f;
  #pragma unroll 8
  for (int k = 0; k < kD; k++) acc = fmaf(ov[k], W[(size_t)k * kD + j], acc);
  out4[b * kD + j] = h[(size_t)(b * kT + kT - 1) * kD + j] + bias[j] + acc;
}

// ---------------- head ----------------
__global__ __launch_bounds__(256) void head_kernel(const float* __restrict__ hl,
                                                   const float* __restrict__ W,
                                                   const float* __restrict__ hb,
                                                   float* __restrict__ out) {
  const int j = blockIdx.x * 256 + threadIdx.x;
  __shared__ float sh[kB * kD];
  for (int i = threadIdx.x; i < kB * kD; i += 256) sh[i] = hl[i];
  __syncthreads();
  float a0 = 0.f, a1 = 0.f, a2 = 0.f, a3 = 0.f;
  #pragma unroll 8
  for (int k = 0; k < kD; k++) {
    const float wv = W[(size_t)k * kC + j];
    a0 = fmaf(sh[k], wv, a0);
    a1 = fmaf(sh[kD + k], wv, a1);
    a2 = fmaf(sh[2 * kD + k], wv, a2);
    a3 = fmaf(sh[3 * kD + k], wv, a3);
  }
  const float bb = hb[j];
  out[j] = a0 + bb;
  out[kC + j] = a1 + bb;
  out[2 * kC + j] = a2 + bb;
  out[3 * kC + j] = a3 + bb;
}

// ---------------- host ----------------
extern "C" void kernel_launch(void* const* d_in, const int* in_sizes, int n_in,
                              void* d_out, int out_size, void* d_ws, size_t ws_size,
                              hipStream_t stream) {
  const int*   tokens = (const int*)d_in[0];
  const float* embW   = (const float*)d_in[1];
  const float* posW   = (const float*)d_in[2];
  const float* ln_g   = (const float*)d_in[3];
  const float* ln_b   = (const float*)d_in[4];
  const float* qkv_W  = (const float*)d_in[5];
  const float* qkv_b  = (const float*)d_in[6];
  const float* out_W  = (const float*)d_in[7];
  const float* out_b  = (const float*)d_in[8];
  const float* lnf_g  = (const float*)d_in[9];
  const float* lnf_b  = (const float*)d_in[10];
  const float* headW  = (const float*)d_in[11];
  const float* headb  = (const float*)d_in[12];
  float* logits = (float*)d_out;

  char* ws = (char*)d_ws;
  float*  h     = (float*)(ws);                    // [8192][1024] f32   32 MiB
  __bf16* hn    = (__bf16*)(ws + 33554432);        // [8192][1024] bf16  16 MiB
  __bf16* qkv   = (__bf16*)(ws + 50331648);        // [8192][2048] bf16 (Q|K) 32 MiB
  __bf16* Vt    = (__bf16*)(ws + 83886080);        // [64][64][2048] bf16 16 MiB
  __bf16* ob    = (__bf16*)(ws + 100663296);       // [8192][1024] bf16  16 MiB
  __bf16* WqkvT = (__bf16*)(ws + 117440512);       // [2][3072][1024] bf16 12 MiB
  __bf16* WoT   = (__bf16*)(ws + 130613248);       // [1024][1024] bf16 2 MiB
  float*  hl4   = (float*)(ws + 132710400);        // [4][1024]
  float*  hl    = (float*)(ws + 132726784);        // [4][1024]
  // flash-l1 partials reuse hn region (dead after l1 GEMMs issued)
  float* part_acc = (float*)(ws + 33554432);       // 512*4096 f32 = 8 MiB
  float* part_ml  = (float*)(ws + 33554432 + 8388608);

  transpose_w_kernel<<<(kD/32)*(k3D/32), 256, 0, stream>>>(qkv_W, WqkvT, kD, k3D);
  transpose_w_kernel<<<(kD/32)*(k3D/32), 256, 0, stream>>>(qkv_W + (size_t)kD*k3D,
                                                           WqkvT + (size_t)k3D*kD, kD, k3D);
  transpose_w_kernel<<<(kD/32)*(kD/32), 256, 0, stream>>>(out_W, WoT, kD, kD);

  embed_kernel<<<kM, 256, 0, stream>>>(tokens, embW, posW, h);

  // ---- layer 0 ----
  ln_kernel<true><<<kM, 256, 0, stream>>>(h, ln_g, ln_b, hn);
  gemm_bt_kernel<true><<<(kM/128)*(k3D/128), 256, 0, stream>>>(
      hn, WqkvT, qkv_b, nullptr, nullptr, qkv, Vt, k3D, kD, kQK, 2048, 1, 0);
  flash_kernel<0><<<kB*kH*16, 256, 0, stream>>>(qkv, Vt, ob, nullptr, nullptr, 16);
  gemm_bt_kernel<false><<<(kM/128)*(kD/128), 256, 0, stream>>>(
      ob, WoT, out_b, h, h, nullptr, nullptr, kD, kD, kD, 1 << 30, 1, 0);

  // ---- layer 1 ----
  ln_kernel<true><<<kM, 256, 0, stream>>>(h, ln_g + kD, ln_b + kD, hn);
  // K,V for all tokens: weight rows 1024..3071; local cols 0-1023 -> K, 1024-2047 -> Vt
  gemm_bt_kernel<true><<<(kM/128)*(2048/128), 256, 0, stream>>>(
      hn, WqkvT + (size_t)k3D*kD + (size_t)kD*kD, qkv_b + k3D + kD,
      nullptr, nullptr, qkv + 1024, Vt, 2048, kD, kQK, 1024, 1, 0);
  // Q only for each batch's last 128 rows
  gemm_bt_kernel<true><<<kB*(kD/128), 256, 0, stream>>>(
      hn, WqkvT + (size_t)k3D*kD, qkv_b + k3D,
      nullptr, nullptr, qkv, nullptr, kD, kD, kQK, 1 << 30, 16, 15);
  flash_kernel<1><<<kB*kH*8, 256, 0, stream>>>(qkv, Vt, nullptr, part_acc, part_ml, 8);
  flash_merge_kernel<<<kB*kH, 256, 0, stream>>>(part_acc, part_ml, ob);
  proj_last_kernel<<<dim3(kD/256, kB), 256, 0, stream>>>(ob, out_W + (size_t)kD*kD,
                                                         out_b + kD, h, hl4);

  ln_kernel<false><<<kB, 256, 0, stream>>>(hl4, lnf_g, lnf_b, hl);
  head_kernel<<<kC/256, 256, 0, stream>>>(hl, headW, headb, logits);
}

// Round 4
// 480.838 us; speedup vs baseline: 1.5860x; 1.1129x over previous
//
#include <hip/hip_runtime.h>

typedef __attribute__((ext_vector_type(8))) __bf16 bf16x8;
typedef __attribute__((ext_vector_type(4))) __bf16 bf16x4;
typedef __attribute__((ext_vector_type(4))) float f32x4;
typedef unsigned long long ull;

static constexpr int kB = 4, kT = 2048, kD = 1024, kH = 16;
static constexpr int kC = 32000, kM = 8192, k3D = 3072, kQK = 2048;

#define MFMA16(a, b, c) __builtin_amdgcn_mfma_f32_16x16x32_bf16((a), (b), (c), 0, 0, 0)

__device__ __forceinline__ void gload_lds16(const __bf16* g, __bf16* l) {
  __builtin_amdgcn_global_load_lds(
      (const __attribute__((address_space(1))) unsigned int*)(const void*)g,
      (__attribute__((address_space(3))) unsigned int*)(void*)l, 16, 0, 0);
}

// ---------------- fused embed + layer-0 LN ----------------
__global__ __launch_bounds__(256) void embed_ln_kernel(const int* __restrict__ tok,
                                                       const float* __restrict__ embW,
                                                       const float* __restrict__ posW,
                                                       const float* __restrict__ g,
                                                       const float* __restrict__ bb,
                                                       float* __restrict__ h,
                                                       __bf16* __restrict__ hn) {
  const int row = blockIdx.x, tid = threadIdx.x;
  const int t = row & (kT - 1);
  const int tk = tok[row];
  const f32x4 e = ((const f32x4*)(embW + (size_t)tk * kD))[tid];
  const f32x4 p = ((const f32x4*)(posW + (size_t)t * kD))[tid];
  const f32x4 xv = e + p;
  ((f32x4*)(h + (size_t)row * kD))[tid] = xv;
  float s  = xv[0] + xv[1] + xv[2] + xv[3];
  float s2 = xv[0]*xv[0] + xv[1]*xv[1] + xv[2]*xv[2] + xv[3]*xv[3];
  #pragma unroll
  for (int off = 1; off < 64; off <<= 1) {
    s  += __shfl_xor(s, off);
    s2 += __shfl_xor(s2, off);
  }
  __shared__ float red[8];
  const int w = tid >> 6;
  if ((tid & 63) == 0) { red[w*2] = s; red[w*2+1] = s2; }
  __syncthreads();
  s  = red[0] + red[2] + red[4] + red[6];
  s2 = red[1] + red[3] + red[5] + red[7];
  const float mu  = s * (1.f / kD);
  const float var = s2 * (1.f / kD) - mu * mu;
  const float rs  = rsqrtf(var + 1e-5f);
  const f32x4 gv = ((const f32x4*)g)[tid];
  const f32x4 bv = ((const f32x4*)bb)[tid];
  bf16x4 o;
  #pragma unroll
  for (int i = 0; i < 4; i++) o[i] = (__bf16)((xv[i] - mu) * rs * gv[i] + bv[i]);
  ((bf16x4*)(hn + (size_t)row * kD))[tid] = o;
}

// ---------------- LayerNorm ----------------
template <bool BF16OUT>
__global__ __launch_bounds__(256) void ln_kernel(const float* __restrict__ x,
                                                 const float* __restrict__ g,
                                                 const float* __restrict__ bb,
                                                 void* __restrict__ outp) {
  const int row = blockIdx.x, tid = threadIdx.x;
  const f32x4 xv = ((const f32x4*)(x + (size_t)row * kD))[tid];
  float s  = xv[0] + xv[1] + xv[2] + xv[3];
  float s2 = xv[0]*xv[0] + xv[1]*xv[1] + xv[2]*xv[2] + xv[3]*xv[3];
  #pragma unroll
  for (int off = 1; off < 64; off <<= 1) {
    s  += __shfl_xor(s, off);
    s2 += __shfl_xor(s2, off);
  }
  __shared__ float red[8];
  const int w = tid >> 6;
  if ((tid & 63) == 0) { red[w*2] = s; red[w*2+1] = s2; }
  __syncthreads();
  s  = red[0] + red[2] + red[4] + red[6];
  s2 = red[1] + red[3] + red[5] + red[7];
  const float mu  = s * (1.f / kD);
  const float var = s2 * (1.f / kD) - mu * mu;
  const float rs  = rsqrtf(var + 1e-5f);
  const f32x4 gv = ((const f32x4*)g)[tid];
  const f32x4 bv = ((const f32x4*)bb)[tid];
  if constexpr (BF16OUT) {
    bf16x4 o;
    #pragma unroll
    for (int i = 0; i < 4; i++) o[i] = (__bf16)((xv[i] - mu) * rs * gv[i] + bv[i]);
    ((bf16x4*)((__bf16*)outp + (size_t)row * kD))[tid] = o;
  } else {
    f32x4 o;
    #pragma unroll
    for (int i = 0; i < 4; i++) o[i] = (xv[i] - mu) * rs * gv[i] + bv[i];
    ((f32x4*)((float*)outp + (size_t)row * kD))[tid] = o;
  }
}

// ---------------- merged weight transposes: f32 [K][N] -> bf16 [N][K] ----------------
__global__ __launch_bounds__(256) void transpose_all_kernel(const float* __restrict__ qkv_W,
                                                            const float* __restrict__ out_W,
                                                            __bf16* __restrict__ WqkvT,
                                                            __bf16* __restrict__ WoT) {
  __shared__ float sh[32][33];
  const int bid = blockIdx.x;
  const float* W; __bf16* WT; int N, tile;
  if (bid < 3072)      { W = qkv_W;                   WT = WqkvT;                    N = k3D; tile = bid; }
  else if (bid < 6144) { W = qkv_W + (size_t)kD*k3D;  WT = WqkvT + (size_t)k3D*kD;   N = k3D; tile = bid - 3072; }
  else                 { W = out_W;                   WT = WoT;                      N = kD;  tile = bid - 6144; }
  const int tx = threadIdx.x & 31, ty = threadIdx.x >> 5;
  const int ntile = N >> 5;
  const int c0 = (tile % ntile) << 5;
  const int r0 = (tile / ntile) << 5;
  #pragma unroll
  for (int i = 0; i < 4; i++) {
    const int r = ty + i * 8;
    sh[r][tx] = W[(size_t)(r0 + r) * N + c0 + tx];
  }
  __syncthreads();
  #pragma unroll
  for (int i = 0; i < 4; i++) {
    const int cc = ty + i * 8;
    WT[(size_t)(c0 + cc) * kD + r0 + tx] = (__bf16)sh[tx][cc];
  }
}

// ---------------- GEMM (m97 structure): C = A @ BT^T + bias ----------------
template <bool OUT_BF16>
__global__ __launch_bounds__(256) void gemm_bt_kernel(const __bf16* __restrict__ A,
                                                      const __bf16* __restrict__ BT,
                                                      const float* __restrict__ bias,
                                                      const float* resid,
                                                      float* outf,
                                                      __bf16* outb,
                                                      __bf16* vtp,
                                                      int N, int K, int ldc, int vt_c0,
                                                      int bm_mult, int bm_add) {
  __shared__ __bf16 As[128 * 64];
  __shared__ __bf16 Bs[128 * 64];
  const int tid = threadIdx.x;
  const int lane = tid & 63, w = tid >> 6;
  int wg = (int)blockIdx.x;
  const int nwg = gridDim.x;
  wg = (wg & 7) * (nwg >> 3) + (wg >> 3);      // bijective XCD swizzle (nwg%8==0)
  const int nbn = N >> 7;
  const int bm = (wg / nbn) * bm_mult + bm_add;
  const int bn = wg % nbn;
  const int wr = (w >> 1) * 64, wc = (w & 1) * 64;
  const int lrow = lane & 15, lk8 = (lane >> 4) * 8;

  const int srow = lane >> 3;
  const int scol = (lane & 7) * 8;
  const __bf16* gA = A + (size_t)(bm * 128) * K;
  const __bf16* gB = BT + (size_t)(bn * 128) * K;

  f32x4 acc[4][4] = {};

  for (int k0 = 0; k0 < K; k0 += 64) {
    __syncthreads();
    #pragma unroll
    for (int i = 0; i < 4; i++) {
      const int c = w * 4 + i;
      const int row = c * 8 + srow;
      gload_lds16(gA + (size_t)row * K + k0 + scol, As + c * 512);
      gload_lds16(gB + (size_t)row * K + k0 + scol, Bs + c * 512);
    }
    __syncthreads();
    #pragma unroll
    for (int ks = 0; ks < 2; ks++) {
      bf16x8 af[4], bf[4];
      #pragma unroll
      for (int mt = 0; mt < 4; mt++)
        af[mt] = *(const bf16x8*)(As + (wr + mt * 16 + lrow) * 64 + ks * 32 + lk8);
      #pragma unroll
      for (int nt = 0; nt < 4; nt++)
        bf[nt] = *(const bf16x8*)(Bs + (wc + nt * 16 + lrow) * 64 + ks * 32 + lk8);
      __builtin_amdgcn_s_setprio(1);
      #pragma unroll
      for (int mt = 0; mt < 4; mt++)
        #pragma unroll
        for (int nt = 0; nt < 4; nt++)
          acc[mt][nt] = MFMA16(af[mt], bf[nt], acc[mt][nt]);
      __builtin_amdgcn_s_setprio(0);
    }
  }

  #pragma unroll
  for (int mt = 0; mt < 4; mt++) {
    const int row0 = bm * 128 + wr + mt * 16 + (lane >> 4) * 4;
    #pragma unroll
    for (int nt = 0; nt < 4; nt++) {
      const int col = bn * 128 + wc + nt * 16 + lrow;
      const float bsv = bias[col];
      if (vtp && col >= vt_c0) {
        const int vd = col - vt_c0;                 // h*64 + d
        const int bb_ = row0 >> 11, t = row0 & (kT - 1);
        bf16x4 pk;
        #pragma unroll
        for (int r = 0; r < 4; r++) pk[r] = (__bf16)(acc[mt][nt][r] + bsv);
        *(bf16x4*)(vtp + ((size_t)((bb_ << 4) + (vd >> 6)) * 64 + (vd & 63)) * kT + t) = pk;
      } else {
        #pragma unroll
        for (int r = 0; r < 4; r++) {
          const size_t idx = (size_t)(row0 + r) * ldc + col;
          const float v = acc[mt][nt][r] + bsv;
          if constexpr (OUT_BF16) {
            outb[idx] = (__bf16)v;
          } else {
            outf[idx] = v + resid[idx];
          }
        }
      }
    }
  }
}

// ---------------- flash attention: swapped QK^T, in-register P, 2-phase prefetch ----------------
// qkv [B*T][2048] = Q|K bf16; vtg [64 bh][64 d][2048 t] bf16.
// MODE 0: paired causal q-tiles {sub, 2*nsub-1-sub}; MODE 1: qt=31, k-chunk split.
template <int MODE>
__global__ __launch_bounds__(256) void flash_kernel(const __bf16* __restrict__ qkv,
                                                    const __bf16* __restrict__ vtg,
                                                    __bf16* __restrict__ o,
                                                    float* __restrict__ part_acc,
                                                    float* __restrict__ part_ml,
                                                    int nsub) {
  constexpr float SC = 0.18033688011112042f;  // (1/8)*log2(e)
  __shared__ __bf16 Qs[64 * 64];
  __shared__ __bf16 Ks[2][64 * 64];
  __shared__ __bf16 Vs[2][64 * 64];
  const int tid = threadIdx.x, lane = tid & 63, w = tid >> 6;
  int wg = (int)blockIdx.x;
  const int nwg = gridDim.x;
  wg = (wg & 7) * (nwg >> 3) + (wg >> 3);
  const int sub = wg % nsub, bh = wg / nsub;
  const int b = bh >> 4, hh = bh & 15;
  const int g = lane >> 4, qown = lane & 15;
  const int sslot = (lane & 7) ^ ((lane >> 3) & 7);   // inverse-swizzled source slot
  const int swz = (qown & 7) << 3;                     // read-side XOR (elements)
  const size_t row0 = (size_t)b * kT;
  const int NS = (MODE == 0) ? 2 : 1;
  const int r8 = lane >> 3;                            // staging row-within-8

  for (int s = 0; s < NS; s++) {
    int qt, ktlo, kthi;
    if constexpr (MODE == 0) {
      qt = s ? (2 * nsub - 1 - sub) : sub;
      ktlo = 0; kthi = qt + 1;
    } else {
      qt = 31; ktlo = sub * 4; kthi = ktlo + 4;
    }

    __syncthreads();   // prior-s LDS reads done
    #pragma unroll
    for (int j = 0; j < 2; j++) {
      const int r = w * 16 + j * 8 + r8;
      gload_lds16(qkv + (row0 + qt * 64 + r) * kQK + hh * 64 + sslot * 8,
                  Qs + (w * 16 + j * 8) * 64);
      gload_lds16(qkv + (row0 + ktlo * 64 + r) * kQK + 1024 + hh * 64 + sslot * 8,
                  Ks[0] + (w * 16 + j * 8) * 64);
      gload_lds16(vtg + ((size_t)bh * 64 + r) * kT + ktlo * 64 + sslot * 8,
                  Vs[0] + (w * 16 + j * 8) * 64);
    }
    __syncthreads();   // Q + first K/V landed
    bf16x8 qf[2];
    #pragma unroll
    for (int ks = 0; ks < 2; ks++) {
      bf16x8 qr = *(const bf16x8*)(Qs + (w * 16 + qown) * 64 + ((ks * 32 + 8 * g) ^ swz));
      #pragma unroll
      for (int i = 0; i < 8; i++) qf[ks][i] = (__bf16)((float)qr[i] * SC);
    }

    float m_run = -1e30f, l_run = 0.f;
    f32x4 acc[4] = {};
    int cur = 0;

    for (int kt = ktlo; kt < kthi; kt++) {
      // prefetch next tile into the other buffer (flies under this iter's compute)
      if (kt + 1 < kthi) {
        #pragma unroll
        for (int j = 0; j < 2; j++) {
          const int r = w * 16 + j * 8 + r8;
          gload_lds16(qkv + (row0 + (kt + 1) * 64 + r) * kQK + 1024 + hh * 64 + sslot * 8,
                      Ks[cur ^ 1] + (w * 16 + j * 8) * 64);
          gload_lds16(vtg + ((size_t)bh * 64 + r) * kT + (kt + 1) * 64 + sslot * 8,
                      Vs[cur ^ 1] + (w * 16 + j * 8) * 64);
        }
      }

      // S^T tile: thread holds S[k = nt*16+4g+r][q = w*16+qown]
      f32x4 sv[4] = {};
      __builtin_amdgcn_s_setprio(1);
      #pragma unroll
      for (int nt = 0; nt < 4; nt++) {
        const int kr = nt * 16 + qown;
        #pragma unroll
        for (int ks = 0; ks < 2; ks++) {
          bf16x8 kf = *(const bf16x8*)(Ks[cur] + kr * 64 + ((ks * 32 + 8 * g) ^ swz));
          sv[nt] = MFMA16(kf, qf[ks], sv[nt]);
        }
      }
      __builtin_amdgcn_s_setprio(0);
      if (kt == qt) {   // wave-uniform causal mask (diagonal tile only)
        #pragma unroll
        for (int nt = 0; nt < 4; nt++)
          #pragma unroll
          for (int r = 0; r < 4; r++)
            if (nt * 16 + 4 * g + r > w * 16 + qown) sv[nt][r] = -1e30f;
      }

      // per-lane row max (one q-row per lane; partials across the 4 lane-groups)
      float mx = -1e30f;
      #pragma unroll
      for (int nt = 0; nt < 4; nt++)
        #pragma unroll
        for (int r = 0; r < 4; r++) mx = fmaxf(mx, sv[nt][r]);
      mx = fmaxf(mx, __shfl_xor(mx, 16));
      mx = fmaxf(mx, __shfl_xor(mx, 32));

      float ps = 0.f;
      ull quad[4];
      if (__all(mx - m_run <= 8.0f)) {
        // deferred: keep m_run, no O-rescale (P bounded by 2^8)
        #pragma unroll
        for (int nt = 0; nt < 4; nt++) {
          union { bf16x4 v; ull u; } qd;
          #pragma unroll
          for (int r = 0; r < 4; r++) {
            const float p = exp2f(sv[nt][r] - m_run);
            ps += p;
            qd.v[r] = (__bf16)p;
          }
          quad[nt] = qd.u;
        }
        ps += __shfl_xor(ps, 16);
        ps += __shfl_xor(ps, 32);
        l_run += ps;
      } else {
        const float mnew = fmaxf(m_run, mx);
        const float fsc = exp2f(m_run - mnew);
        m_run = mnew;
        #pragma unroll
        for (int nt = 0; nt < 4; nt++) {
          union { bf16x4 v; ull u; } qd;
          #pragma unroll
          for (int r = 0; r < 4; r++) {
            const float p = exp2f(sv[nt][r] - mnew);
            ps += p;
            qd.v[r] = (__bf16)p;
          }
          quad[nt] = qd.u;
        }
        ps += __shfl_xor(ps, 16);
        ps += __shfl_xor(ps, 32);
        l_run = l_run * fsc + ps;
        float fr[4];
        #pragma unroll
        for (int r = 0; r < 4; r++) fr[r] = __shfl(fsc, 20 * g + r);
        #pragma unroll
        for (int nt = 0; nt < 4; nt++)
          #pragma unroll
          for (int r = 0; r < 4; r++) acc[nt][r] *= fr[r];
      }

      // assemble PV A-fragment: lane needs P[q=qown][k = ks*32 + 8g + i]
      bf16x8 pf[2];
      #pragma unroll
      for (int ks = 0; ks < 2; ks++) {
        const int src = (g & 1) * 32 + qown;
        const ull t0 = __shfl(quad[2 * ks],     src);
        const ull t1 = __shfl(quad[2 * ks + 1], src);
        const ull lo = (g & 2) ? t1 : t0;
        const ull t2 = __shfl(quad[2 * ks],     src + 16);
        const ull t3 = __shfl(quad[2 * ks + 1], src + 16);
        const ull hi = (g & 2) ? t3 : t2;
        union { ull u[2]; bf16x8 v; } pk;
        pk.u[0] = lo; pk.u[1] = hi;
        pf[ks] = pk.v;
      }

      __builtin_amdgcn_s_setprio(1);
      #pragma unroll
      for (int nt = 0; nt < 4; nt++) {
        const int vr = nt * 16 + qown;
        #pragma unroll
        for (int ks = 0; ks < 2; ks++) {
          bf16x8 vf = *(const bf16x8*)(Vs[cur] + vr * 64 + ((ks * 32 + 8 * g) ^ swz));
          acc[nt] = MFMA16(pf[ks], vf, acc[nt]);
        }
      }
      __builtin_amdgcn_s_setprio(0);

      __syncthreads();   // drains prefetch vmcnt; all waves done reading buf[cur]
      cur ^= 1;
    }  // kt

    if constexpr (MODE == 0) {
      const float li = 1.f / l_run;
      float lr[4];
      #pragma unroll
      for (int r = 0; r < 4; r++) lr[r] = __shfl(li, 20 * g + r);
      #pragma unroll
      for (int r = 0; r < 4; r++) {
        const int t = qt * 64 + w * 16 + 4 * g + r;
        #pragma unroll
        for (int nt = 0; nt < 4; nt++)
          o[(row0 + t) * kD + hh * 64 + nt * 16 + qown] = (__bf16)(acc[nt][r] * lr[r]);
      }
    } else {
      const int tile = bh * nsub + sub;
      #pragma unroll
      for (int r = 0; r < 4; r++) {
        const int rr = w * 16 + 4 * g + r;
        #pragma unroll
        for (int nt = 0; nt < 4; nt++)
          part_acc[(size_t)tile * 4096 + rr * 64 + nt * 16 + qown] = acc[nt][r];
      }
      if (g == 0) {
        part_ml[tile * 128 + w * 16 + qown] = m_run;
        part_ml[tile * 128 + 64 + w * 16 + qown] = l_run;
      }
    }
  }  // s
}

// ---------------- merge k-split flash partials (qt=31) ----------------
__global__ __launch_bounds__(256) void flash_merge_kernel(const float* __restrict__ part_acc,
                                                          const float* __restrict__ part_ml,
                                                          __bf16* __restrict__ o) {
  const int bh = blockIdx.x, b = bh >> 4, hh = bh & 15;
  for (int e = threadIdx.x; e < 4096; e += 256) {
    const int row = e >> 6, d = e & 63;
    float mstar = -1e30f;
    #pragma unroll
    for (int kc = 0; kc < 8; kc++)
      mstar = fmaxf(mstar, part_ml[(bh * 8 + kc) * 128 + row]);
    float lstar = 0.f, osum = 0.f;
    #pragma unroll
    for (int kc = 0; kc < 8; kc++) {
      const float wgt = exp2f(part_ml[(bh * 8 + kc) * 128 + row] - mstar);
      lstar += wgt * part_ml[(bh * 8 + kc) * 128 + 64 + row];
      osum  += wgt * part_acc[(size_t)(bh * 8 + kc) * 4096 + e];
    }
    o[(size_t)(b * kT + 1984 + row) * kD + hh * 64 + d] = (__bf16)(osum / lstar);
  }
}

// ---------------- layer-2 out-proj, last token only ----------------
__global__ __launch_bounds__(256) void proj_last_kernel(const __bf16* __restrict__ o,
                                                        const float* __restrict__ W,
                                                        const float* __restrict__ bias,
                                                        const float* __restrict__ h,
                                                        float* __restrict__ out4) {
  const int b = blockIdx.y;
  const int j = blockIdx.x * 256 + threadIdx.x;
  __shared__ float ov[kD];
  const __bf16* orow = o + (size_t)(b * kT + kT - 1) * kD;
  for (int i = threadIdx.x; i < kD; i += 256) ov[i] = (float)orow[i];
  __syncthreads();
  float acc = 0.f;
  #pragma unroll 8
  for (int k = 0; k < kD; k++) acc = fmaf(ov[k], W[(size_t)k * kD + j], acc);
  out4[b * kD + j] = h[(size_t)(b * kT + kT - 1) * kD + j] + bias[j] + acc;
}

// ---------------- head: k-split GEMV, 500 blocks (64 cols x 4 k-chunks each) ----------------
__global__ __launch_bounds__(256) void head_kernel(const float* __restrict__ hl,
                                                   const float* __restrict__ W,
                                                   const float* __restrict__ hb,
                                                   float* __restrict__ out) {
  const int jj = threadIdx.x & 63, ks = threadIdx.x >> 6;
  const int j = blockIdx.x * 64 + jj;
  __shared__ float sh[kB * kD];
  __shared__ float red[4][kB][64];
  for (int i = threadIdx.x; i < kB * kD; i += 256) sh[i] = hl[i];
  __syncthreads();
  float a[kB] = {};
  const int k0 = ks * 256;
  #pragma unroll 4
  for (int k = k0; k < k0 + 256; k++) {
    const float wv = W[(size_t)k * kC + j];
    #pragma unroll
    for (int bb = 0; bb < kB; bb++) a[bb] = fmaf(sh[bb * kD + k], wv, a[bb]);
  }
  #pragma unroll
  for (int bb = 0; bb < kB; bb++) red[ks][bb][jj] = a[bb];
  __syncthreads();
  if (ks == 0) {
    const float bv = hb[j];
    #pragma unroll
    for (int bb = 0; bb < kB; bb++)
      out[(size_t)bb * kC + j] = red[0][bb][jj] + red[1][bb][jj] + red[2][bb][jj] + red[3][bb][jj] + bv;
  }
}

// ---------------- host ----------------
extern "C" void kernel_launch(void* const* d_in, const int* in_sizes, int n_in,
                              void* d_out, int out_size, void* d_ws, size_t ws_size,
                              hipStream_t stream) {
  const int*   tokens = (const int*)d_in[0];
  const float* embW   = (const float*)d_in[1];
  const float* posW   = (const float*)d_in[2];
  const float* ln_g   = (const float*)d_in[3];
  const float* ln_b   = (const float*)d_in[4];
  const float* qkv_W  = (const float*)d_in[5];
  const float* qkv_b  = (const float*)d_in[6];
  const float* out_W  = (const float*)d_in[7];
  const float* out_b  = (const float*)d_in[8];
  const float* lnf_g  = (const float*)d_in[9];
  const float* lnf_b  = (const float*)d_in[10];
  const float* headW  = (const float*)d_in[11];
  const float* headb  = (const float*)d_in[12];
  float* logits = (float*)d_out;

  char* ws = (char*)d_ws;
  float*  h     = (float*)(ws);                    // [8192][1024] f32   32 MiB
  __bf16* hn    = (__bf16*)(ws + 33554432);        // [8192][1024] bf16  16 MiB
  __bf16* qkv   = (__bf16*)(ws + 50331648);        // [8192][2048] bf16 (Q|K) 32 MiB
  __bf16* Vt    = (__bf16*)(ws + 83886080);        // [64][64][2048] bf16 16 MiB
  __bf16* ob    = (__bf16*)(ws + 100663296);       // [8192][1024] bf16  16 MiB
  __bf16* WqkvT = (__bf16*)(ws + 117440512);       // [2][3072][1024] bf16 12 MiB
  __bf16* WoT   = (__bf16*)(ws + 130613248);       // [1024][1024] bf16 2 MiB
  float*  hl4   = (float*)(ws + 132710400);        // [4][1024]
  float*  hl    = (float*)(ws + 132726784);        // [4][1024]
  float* part_acc = (float*)(ws + 33554432);       // reuse hn region after l1 GEMMs
  float* part_ml  = (float*)(ws + 33554432 + 8388608);

  transpose_all_kernel<<<7168, 256, 0, stream>>>(qkv_W, out_W, WqkvT, WoT);
  embed_ln_kernel<<<kM, 256, 0, stream>>>(tokens, embW, posW, ln_g, ln_b, h, hn);

  // ---- layer 0 ----
  gemm_bt_kernel<true><<<(kM/128)*(k3D/128), 256, 0, stream>>>(
      hn, WqkvT, qkv_b, nullptr, nullptr, qkv, Vt, k3D, kD, kQK, 2048, 1, 0);
  flash_kernel<0><<<kB*kH*16, 256, 0, stream>>>(qkv, Vt, ob, nullptr, nullptr, 16);
  gemm_bt_kernel<false><<<(kM/128)*(kD/128), 256, 0, stream>>>(
      ob, WoT, out_b, h, h, nullptr, nullptr, kD, kD, kD, 1 << 30, 1, 0);

  // ---- layer 1 ----
  ln_kernel<true><<<kM, 256, 0, stream>>>(h, ln_g + kD, ln_b + kD, hn);
  gemm_bt_kernel<true><<<(kM/128)*(2048/128), 256, 0, stream>>>(
      hn, WqkvT + (size_t)k3D*kD + (size_t)kD*kD, qkv_b + k3D + kD,
      nullptr, nullptr, qkv + 1024, Vt, 2048, kD, kQK, 1024, 1, 0);
  gemm_bt_kernel<true><<<kB*(kD/128), 256, 0, stream>>>(
      hn, WqkvT + (size_t)k3D*kD, qkv_b + k3D,
      nullptr, nullptr, qkv, nullptr, kD, kD, kQK, 1 << 30, 16, 15);
  flash_kernel<1><<<kB*kH*8, 256, 0, stream>>>(qkv, Vt, nullptr, part_acc, part_ml, 8);
  flash_merge_kernel<<<kB*kH, 256, 0, stream>>>(part_acc, part_ml, ob);
  proj_last_kernel<<<dim3(kD/256, kB), 256, 0, stream>>>(ob, out_W + (size_t)kD*kD,
                                                         out_b + kD, h, hl4);

  ln_kernel<false><<<kB, 256, 0, stream>>>(hl4, lnf_g, lnf_b, hl);
  head_kernel<<<500, 256, 0, stream>>>(hl, headW, headb, logits);
}